// Round 4
// baseline (1619.652 us; speedup 1.0000x reference)
//
#include <hip/hip_runtime.h>
#include <math.h>

#define TT 2048
#define EE 768
#define HNN 12
#define HSS 64
#define NLAYER 6
#define FFD 3072
#define QKVN 2304

constexpr float LN_EPS = 1e-5f;
constexpr float ATT_SCALE = 0.03608439182435161f; // 1/sqrt(768) (reference divides by sqrt(n_embed))
// log2-domain scale: exp(x*A) == exp2(x*A*log2e)
constexpr float ATT_SCALE_L2E = 0.03608439182435161f * 1.4426950408889634f;

typedef __attribute__((ext_vector_type(8))) short bf16x8;
typedef __attribute__((ext_vector_type(4))) float f32x4;

__device__ __forceinline__ ushort f2bf(float f) {
    union { float f; uint u; } c; c.f = f;
    const uint u = c.u;
    return (ushort)((u + 0x7fffu + ((u >> 16) & 1u)) >> 16);
}

__device__ __forceinline__ void gload16(const void* g, void* l) {
    __builtin_amdgcn_global_load_lds((const __attribute__((address_space(1))) void*)g,
                                     (__attribute__((address_space(3))) void*)l, 16, 0, 0);
}

// ---------------------------------------------------------------- copy ----
__global__ __launch_bounds__(256) void copy4_kernel(float4* __restrict__ dst,
                                                    const float4* __restrict__ src, int n4) {
    int i = blockIdx.x * 256 + threadIdx.x;
    if (i < n4) dst[i] = src[i];
}

// ----------------------------------------------------------- layernorm ----
// one block (256 thr) per token; E=768 = 3*256.  fp32 in -> bf16 out.
__global__ __launch_bounds__(256) void ln_kernel(const float* __restrict__ in,
                                                 const float* __restrict__ g,
                                                 const float* __restrict__ b,
                                                 ushort* __restrict__ out) {
    __shared__ float red[8];
    const int t = blockIdx.x;
    const int tid = threadIdx.x;
    const float* row = in + (size_t)t * EE;
    float v0 = row[tid], v1 = row[tid + 256], v2 = row[tid + 512];
    float s = v0 + v1 + v2;
#pragma unroll
    for (int m = 1; m < 64; m <<= 1) s += __shfl_xor(s, m, 64);
    if ((tid & 63) == 0) red[tid >> 6] = s;
    __syncthreads();
    const float mean = (red[0] + red[1] + red[2] + red[3]) * (1.0f / EE);
    const float d0 = v0 - mean, d1 = v1 - mean, d2 = v2 - mean;
    float qq = d0 * d0 + d1 * d1 + d2 * d2;
#pragma unroll
    for (int m = 1; m < 64; m <<= 1) qq += __shfl_xor(qq, m, 64);
    __syncthreads();
    if ((tid & 63) == 0) red[tid >> 6] = qq;
    __syncthreads();
    const float var = (red[0] + red[1] + red[2] + red[3]) * (1.0f / EE);
    const float rstd = rsqrtf(var + LN_EPS);
    ushort* orow = out + (size_t)t * EE;
    orow[tid]       = f2bf(d0 * rstd * g[tid]       + b[tid]);
    orow[tid + 256] = f2bf(d1 * rstd * g[tid + 256] + b[tid + 256]);
    orow[tid + 512] = f2bf(d2 * rstd * g[tid + 512] + b[tid + 512]);
}

// --------------------------------------------------- weight pack (fp32->bf16^T)
// dst[n][k] (bf16, row stride dld) = src[k][n] (fp32, row stride sld), 64x64 tile
__device__ __forceinline__ void transpose64(const float* __restrict__ src, int sld,
                                            ushort* __restrict__ dst, int dld,
                                            int k0, int n0, int tid) {
    __shared__ float t[64][68];
#pragma unroll
    for (int p = 0; p < 4; p++) {
        const int kr = p * 16 + (tid >> 4);
        *(float4*)&t[kr][(tid & 15) * 4] =
            *(const float4*)&src[(size_t)(k0 + kr) * sld + n0 + (tid & 15) * 4];
    }
    __syncthreads();
#pragma unroll
    for (int q = 0; q < 2; q++) {
        const int nl = q * 32 + (tid >> 3);
        const int kc = (tid & 7) * 8;
        ushort v[8];
#pragma unroll
        for (int j = 0; j < 8; j++) v[j] = f2bf(t[kc + j][nl]);
        uint4 o;
        o.x = (uint)v[0] | ((uint)v[1] << 16);
        o.y = (uint)v[2] | ((uint)v[3] << 16);
        o.z = (uint)v[4] | ((uint)v[5] << 16);
        o.w = (uint)v[6] | ((uint)v[7] << 16);
        *(uint4*)&dst[(size_t)(n0 + nl) * dld + k0 + kc] = o;
    }
}

__global__ __launch_bounds__(256) void pack_t_kernel(const float* __restrict__ src, int sld,
                                                     ushort* __restrict__ dst, int dld) {
    transpose64(src, sld, dst, dld, blockIdx.x * 64, blockIdx.y * 64, threadIdx.x);
}

// qkv weights [HN][E][HS] (3 tensors) -> Wqkv_t[2304][768] bf16 (row n = which*768+h*64+s)
__global__ __launch_bounds__(256) void pack_qkv_kernel(const float* __restrict__ wq,
                                                       const float* __restrict__ wk,
                                                       const float* __restrict__ wv,
                                                       ushort* __restrict__ dst) {
    const int z = blockIdx.z;
    const int which = z / HNN, hd = z % HNN;
    const float* src = (which == 0 ? wq : which == 1 ? wk : wv) + (size_t)hd * EE * HSS;
    ushort* d = dst + (size_t)(which * EE + hd * HSS) * EE;
    transpose64(src, HSS, d, EE, blockIdx.x * 64, 0, threadIdx.x);
}

// ------------------------------------------------------------ V transpose ----
// qkvb V-section [T][2304] (cols 1536+h*64+d) -> vT[12][64][2048] ([head][d][t])
// wave lanes = 64 consecutive d for one head -> reads are 128B-contiguous rows;
// writes are 16B per lane at 4KB stride (3MB total, L2-absorbed).
__global__ __launch_bounds__(256) void vtrans_kernel(const ushort* __restrict__ qkv,
                                                     ushort* __restrict__ vT) {
    const int t = blockIdx.x * 256 + threadIdx.x;  // 0..196607
    const int d = t & 63;
    const int rest = t >> 6;
    const int tb = rest & 255;   // token block of 8
    const int hd = rest >> 8;    // 0..11
    const ushort* src = qkv + 1536 + hd * 64 + d;
    ushort v[8];
#pragma unroll
    for (int j = 0; j < 8; j++) v[j] = src[(size_t)(tb * 8 + j) * QKVN];
    uint4 o;
    o.x = (uint)v[0] | ((uint)v[1] << 16);
    o.y = (uint)v[2] | ((uint)v[3] << 16);
    o.z = (uint)v[4] | ((uint)v[5] << 16);
    o.w = (uint)v[6] | ((uint)v[7] << 16);
    *(uint4*)&vT[((size_t)hd * 64 + d) * TT + tb * 8] = o;
}

// ---------------------------------------------------------- bf16 GEMM ----
// C[M,N] = epi(A[M,K] @ Bt[N,K]^T + bias).  128x128 tile, BK=32, 4 waves,
// XCD-contiguous remap, 2-phase pipelined K-loop, optional split-K (EPI=1).
template <int EPI>
__global__ __launch_bounds__(256) void gemm_bf16(const ushort* __restrict__ A,
                                                 const ushort* __restrict__ Bt,
                                                 const float* __restrict__ b0,
                                                 const float* __restrict__ b1,
                                                 const float* __restrict__ b2,
                                                 float* __restrict__ outF,
                                                 ushort* __restrict__ outB,
                                                 int N, int K,
                                                 int nby, int KS, int Kslice) {
    __shared__ ushort Al[2][128 * 32];
    __shared__ ushort Bl[2][128 * 32];
    const int tid = threadIdx.x;
    const int wave = tid >> 6, lane = tid & 63;
    const int wm = wave >> 1, wn = wave & 1;
    const int l15 = lane & 15, q4 = lane >> 4;

    const int nwg = gridDim.x;
    const int wgid = ((int)blockIdx.x & 7) * (nwg >> 3) + ((int)blockIdx.x >> 3);
    const int mb = wgid % nby;
    const int t2 = wgid / nby;
    const int ks = t2 % KS;
    const int nb = t2 / KS;
    const int m0 = mb * 128, n0 = nb * 128;
    const int kbase = ks * Kslice;

    const int srow = lane >> 2;
    const int scb = (lane & 3) ^ ((lane >> 3) & 3);
    const ushort* Ag0 = A + (size_t)(m0 + wave * 16 + srow) * K + kbase + scb * 8;
    const ushort* Ag1 = Ag0 + (size_t)64 * K;
    const ushort* Bg0 = Bt + (size_t)(n0 + wave * 16 + srow) * K + kbase + scb * 8;
    const ushort* Bg1 = Bg0 + (size_t)64 * K;

    auto stage = [&](int buf, int kk) {
        const int off = kk * 32;
        gload16(Ag0 + off, &Al[buf][(wave * 16) * 32]);
        gload16(Ag1 + off, &Al[buf][(64 + wave * 16) * 32]);
        gload16(Bg0 + off, &Bl[buf][(wave * 16) * 32]);
        gload16(Bg1 + off, &Bl[buf][(64 + wave * 16) * 32]);
    };

    f32x4 acc[4][4];
#pragma unroll
    for (int i = 0; i < 4; i++)
#pragma unroll
        for (int j = 0; j < 4; j++) acc[i][j] = (f32x4){0.f, 0.f, 0.f, 0.f};

    stage(0, 0);
    __syncthreads();

    const int niter = Kslice >> 5;
    const int cq = (q4 ^ ((l15 >> 1) & 3)) * 8;

    for (int i = 0; i < niter; i++) {
        const int buf = i & 1;
        if (i + 1 < niter) stage(buf ^ 1, i + 1);
        bf16x8 af[4], bfr[4];
#pragma unroll
        for (int ii = 0; ii < 4; ii++)
            af[ii] = *(const bf16x8*)&Al[buf][(wm * 64 + ii * 16 + l15) * 32 + cq];
#pragma unroll
        for (int j = 0; j < 4; j++)
            bfr[j] = *(const bf16x8*)&Bl[buf][(wn * 64 + j * 16 + l15) * 32 + cq];
#pragma unroll
        for (int ii = 0; ii < 4; ii++)
#pragma unroll
            for (int j = 0; j < 4; j++)
                acc[ii][j] = __builtin_amdgcn_mfma_f32_16x16x32_bf16(af[ii], bfr[j], acc[ii][j], 0, 0, 0);
        __syncthreads();
    }

#pragma unroll
    for (int i = 0; i < 4; i++) {
        const int row = m0 + wm * 64 + i * 16 + q4 * 4;
#pragma unroll
        for (int j = 0; j < 4; j++) {
            const int col = n0 + wn * 64 + j * 16 + l15;
            float bias;
            if constexpr (EPI == 0)
                bias = (col < 768) ? b0[col] : (col < 1536 ? b1[col - 768] : b2[col - 1536]);
            else
                bias = (EPI == 1 && ks != 0) ? 0.f : b0[col];
#pragma unroll
            for (int r = 0; r < 4; r++) {
                const float v = acc[i][j][r] + bias;
                const size_t idx = (size_t)(row + r) * N + col;
                if constexpr (EPI == 0) {
                    outB[idx] = f2bf(v);
                } else if constexpr (EPI == 1) {
                    atomicAdd(&outF[idx], v);
                } else if constexpr (EPI == 2) {
                    outB[idx] = f2bf(0.5f * v * (1.0f + erff(v * 0.70710678118654752f)));
                } else {
                    outF[idx] = v;
                }
            }
        }
    }
}

// ----------------------------------------------------- MFMA attention ----
// R7: barrier-free per-wave flash attention.
//  - One WAVE per (head, 16-row q-tile) task: 12*128 = 1536 tasks, 384 blocks
//    of 4 independent waves.  NO __syncthreads in the main loop.
//  - K streamed global->reg, double-buffered (prefetch kt+1 before softmax);
//    V^T streamed global->reg from pre-transposed vT (contiguous B-fragments),
//    single-buffered (QK^T+softmax covers its latency).
//  - Swapped QK^T (lane = one q-row); softmax with pairwise trees + exp2
//    (log2e folded into scale); 2 shfl_xor per reduction.
//  - Ps roundtrip: rotation swizzle (store uint o of row r at (o+4r)&31) ->
//    verified bank-optimal: b64 writes 4 lanes/bank-pair, b128 reads 8/quad.
//  - Task map: XCD x owns head x + half of head 8+(x>>1) (1MB/XCD, L2-resident);
//    qt-descending ranks, block r gets ranks {r, 48+r, 96+r, 144+r} (balance,
//    big blocks dispatched first).
__global__ __launch_bounds__(256, 2) void attn_mfma(const ushort* __restrict__ qkv,
                                                    const ushort* __restrict__ vT,
                                                    ushort* __restrict__ o_bf) {
    __shared__ __align__(16) uint Ps[4][16 * 36];

    const int tid = threadIdx.x;
    const int wave = tid >> 6, lane = tid & 63;
    const int l15 = lane & 15, q4 = lane >> 4;

    // task decode
    const int x = (int)blockIdx.x & 7, r = (int)blockIdx.x >> 3;
    const int rho = wave * 48 + r;  // 0..191
    int head, qi;
    if (rho < 128) { head = x;           qi = 127 - rho; }
    else           { head = 8 + (x >> 1); qi = 2 * (191 - rho) + (x & 1); }
    const int nkt = (qi >> 2) + 1;
    const int qrow_g = qi * 16 + l15;

    // Q fragments (B-operand of swapped QK^T)
    const ushort* qp = qkv + (size_t)qrow_g * QKVN + head * 64;
    const bf16x8 qa0 = *(const bf16x8*)&qp[q4 * 8];
    const bf16x8 qa1 = *(const bf16x8*)&qp[32 + q4 * 8];

    // per-lane K / V^T bases
    const ushort* kbase = qkv + 768 + head * 64 + (size_t)l15 * QKVN + q4 * 8;
    const ushort* vbase = vT + ((size_t)head * 64 + l15) * TT + q4 * 8;

    float m_i = -1e30f, l_i = 0.f;
    f32x4 oacc[4];
#pragma unroll
    for (int n = 0; n < 4; n++) oacc[n] = (f32x4){0.f, 0.f, 0.f, 0.f};

    bf16x8 kA[8], kB[8], vC[8];
    // prologue: K tile 0
#pragma unroll
    for (int n = 0; n < 4; n++)
#pragma unroll
        for (int kb = 0; kb < 2; kb++)
            kA[n * 2 + kb] = *(const bf16x8*)(kbase + (size_t)(n * 16) * QKVN + kb * 32);

    uint* psrow = &Ps[wave][l15 * 36];

    auto body = [&](bf16x8* kc, bf16x8* kn, int kt) {
        // V^T for current tile (latency covered by QK^T + softmax)
        const ushort* vp = vbase + kt * 64;
#pragma unroll
        for (int n = 0; n < 4; n++)
#pragma unroll
            for (int kb = 0; kb < 2; kb++)
                vC[n * 2 + kb] = *(const bf16x8*)(vp + (size_t)(n * 16) * TT + kb * 32);
        // prefetch K for next tile
        if (kt + 1 < nkt) {
            const ushort* kp = kbase + (size_t)(kt + 1) * 64 * QKVN;
#pragma unroll
            for (int n = 0; n < 4; n++)
#pragma unroll
                for (int kb = 0; kb < 2; kb++)
                    kn[n * 2 + kb] = *(const bf16x8*)(kp + (size_t)(n * 16) * QKVN + kb * 32);
        }
        // S^T = K Q^T : lane -> q-row l15, keys n*16 + q4*4 + rr
        f32x4 s[4];
#pragma unroll
        for (int n = 0; n < 4; n++) {
            f32x4 a = (f32x4){0.f, 0.f, 0.f, 0.f};
            a = __builtin_amdgcn_mfma_f32_16x16x32_bf16(kc[n * 2], qa0, a, 0, 0, 0);
            a = __builtin_amdgcn_mfma_f32_16x16x32_bf16(kc[n * 2 + 1], qa1, a, 0, 0, 0);
            s[n] = a;
        }
        // scale into log2 domain + causal mask
        float pe[16];
        const bool diag = (kt == nkt - 1);
#pragma unroll
        for (int n = 0; n < 4; n++) {
            const int k0 = kt * 64 + n * 16 + q4 * 4;
#pragma unroll
            for (int rr = 0; rr < 4; rr++) {
                float xv = s[n][rr] * ATT_SCALE_L2E;
                if (diag && (k0 + rr) > qrow_g) xv = -1e30f;
                pe[n * 4 + rr] = xv;
            }
        }
        // row max: pairwise tree + 2 shfl
        float t8[8];
#pragma unroll
        for (int i = 0; i < 8; i++) t8[i] = fmaxf(pe[i], pe[i + 8]);
        float mx = fmaxf(fmaxf(fmaxf(t8[0], t8[4]), fmaxf(t8[1], t8[5])),
                         fmaxf(fmaxf(t8[2], t8[6]), fmaxf(t8[3], t8[7])));
        mx = fmaxf(mx, __shfl_xor(mx, 16, 64));
        mx = fmaxf(mx, __shfl_xor(mx, 32, 64));
        const float nm = fmaxf(m_i, mx);
        const float al = exp2f(m_i - nm);
#pragma unroll
        for (int i = 0; i < 16; i++) pe[i] = exp2f(pe[i] - nm);
        float s8[8];
#pragma unroll
        for (int i = 0; i < 8; i++) s8[i] = pe[i] + pe[i + 8];
        float rs = ((s8[0] + s8[4]) + (s8[1] + s8[5])) + ((s8[2] + s8[6]) + (s8[3] + s8[7]));
        rs += __shfl_xor(rs, 16, 64);
        rs += __shfl_xor(rs, 32, 64);
        l_i = l_i * al + rs;
        m_i = nm;
        // alpha for O-rows q4*4+rr
        float alr[4];
#pragma unroll
        for (int rr = 0; rr < 4; rr++) alr[rr] = __shfl(al, q4 * 4 + rr, 64);
#pragma unroll
        for (int n = 0; n < 4; n++) {
            oacc[n][0] *= alr[0];
            oacc[n][1] *= alr[1];
            oacc[n][2] *= alr[2];
            oacc[n][3] *= alr[3];
        }
        // P -> A-fragments via per-wave LDS, rotation-swizzled (bank-optimal)
#pragma unroll
        for (int n = 0; n < 4; n++) {
            uint2 d2;
            d2.x = (uint)f2bf(pe[n * 4 + 0]) | ((uint)f2bf(pe[n * 4 + 1]) << 16);
            d2.y = (uint)f2bf(pe[n * 4 + 2]) | ((uint)f2bf(pe[n * 4 + 3]) << 16);
            *(uint2*)&psrow[(8 * n + 2 * q4 + 4 * l15) & 31] = d2;
        }
        const bf16x8 pa0 = *(const bf16x8*)&psrow[(4 * q4 + 4 * l15) & 31];
        const bf16x8 pa1 = *(const bf16x8*)&psrow[(16 + 4 * q4 + 4 * l15) & 31];
        // O += P V
#pragma unroll
        for (int n = 0; n < 4; n++) {
            oacc[n] = __builtin_amdgcn_mfma_f32_16x16x32_bf16(pa0, vC[n * 2], oacc[n], 0, 0, 0);
            oacc[n] = __builtin_amdgcn_mfma_f32_16x16x32_bf16(pa1, vC[n * 2 + 1], oacc[n], 0, 0, 0);
        }
    };

    int kt = 0;
    for (;;) {
        body(kA, kB, kt);
        if (++kt >= nkt) break;
        body(kB, kA, kt);
        if (++kt >= nkt) break;
    }

    float lrec[4];
#pragma unroll
    for (int rr = 0; rr < 4; rr++) lrec[rr] = 1.0f / __shfl(l_i, q4 * 4 + rr, 64);
#pragma unroll
    for (int n = 0; n < 4; n++)
#pragma unroll
        for (int rr = 0; rr < 4; rr++)
            o_bf[(size_t)(qi * 16 + q4 * 4 + rr) * EE + head * 64 + n * 16 + l15] =
                f2bf(oacc[n][rr] * lrec[rr]);
}

// ---------------------------------------------------------------- head ----
__global__ __launch_bounds__(256) void head_kernel(const float* __restrict__ x,
                                                   const float* __restrict__ hw,
                                                   const float* __restrict__ hb,
                                                   float* __restrict__ out) {
    __shared__ float red[8];
    const int t = blockIdx.x, tid = threadIdx.x;
    const float* row = x + (size_t)t * EE;
    float s = row[tid] * hw[tid] + row[tid + 256] * hw[tid + 256] + row[tid + 512] * hw[tid + 512];
#pragma unroll
    for (int m = 1; m < 64; m <<= 1) s += __shfl_xor(s, m, 64);
    if ((tid & 63) == 0) red[tid >> 6] = s;
    __syncthreads();
    if (tid == 0) out[t] = red[0] + red[1] + red[2] + red[3] + hb[0];
}

// -------------------------------------------------------------- launch ----
extern "C" void kernel_launch(void* const* d_in, const int* in_sizes, int n_in,
                              void* d_out, int out_size, void* d_ws, size_t ws_size,
                              hipStream_t stream) {
    const float* idx   = (const float*)d_in[0];
    const float* wq    = (const float*)d_in[2];
    const float* bq    = (const float*)d_in[3];
    const float* wk    = (const float*)d_in[4];
    const float* bk    = (const float*)d_in[5];
    const float* wv    = (const float*)d_in[6];
    const float* bv    = (const float*)d_in[7];
    const float* wproj = (const float*)d_in[8];
    const float* bproj = (const float*)d_in[9];
    const float* ln1g  = (const float*)d_in[10];
    const float* ln1b  = (const float*)d_in[11];
    const float* ln2g  = (const float*)d_in[12];
    const float* ln2b  = (const float*)d_in[13];
    const float* w1    = (const float*)d_in[14];
    const float* b1    = (const float*)d_in[15];
    const float* w2    = (const float*)d_in[16];
    const float* b2    = (const float*)d_in[17];
    const float* lnfg  = (const float*)d_in[18];
    const float* lnfb  = (const float*)d_in[19];
    const float* fw1   = (const float*)d_in[20];
    const float* fb1   = (const float*)d_in[21];
    const float* fw2   = (const float*)d_in[22];
    const float* fb2   = (const float*)d_in[23];
    const float* hw    = (const float*)d_in[24];
    const float* hb    = (const float*)d_in[25];
    float* out = (float*)d_out;

    // ---- workspace carve (~50 MB) ----
    char* p = (char*)d_ws;
    auto alloc = [&](size_t bytes) { void* r = (void*)p; p += (bytes + 255) & ~(size_t)255; return r; };
    float*  x     = (float*)alloc((size_t)TT * EE * 4);
    ushort* h_bf  = (ushort*)alloc((size_t)TT * EE * 2);
    ushort* qkvb  = (ushort*)alloc((size_t)TT * QKVN * 2);
    ushort* o_bf  = (ushort*)alloc((size_t)TT * EE * 2);
    ushort* ffb   = (ushort*)alloc((size_t)TT * FFD * 2);
    ushort* Wqkv  = (ushort*)alloc((size_t)QKVN * EE * 2);
    ushort* Wproj = (ushort*)alloc((size_t)EE * EE * 2);
    ushort* W1t   = (ushort*)alloc((size_t)FFD * EE * 2);
    ushort* W2t   = (ushort*)alloc((size_t)EE * FFD * 2);
    ushort* vTb   = (ushort*)alloc((size_t)HNN * HSS * TT * 2);

    // only batch 3 contributes to the output (logits[-1]; no cross-batch mixing)
    copy4_kernel<<<dim3((TT * EE / 4 + 255) / 256), dim3(256), 0, stream>>>(
        (float4*)x, (const float4*)(idx + (size_t)3 * TT * EE), TT * EE / 4);

    for (int l = 0; l < NLAYER; l++) {
        const size_t lw = (size_t)l;
        pack_qkv_kernel<<<dim3(12, 1, 36), dim3(256), 0, stream>>>(
            wq + lw * HNN * EE * HSS, wk + lw * HNN * EE * HSS, wv + lw * HNN * EE * HSS, Wqkv);
        pack_t_kernel<<<dim3(12, 12), dim3(256), 0, stream>>>(wproj + lw * EE * EE, EE, Wproj, EE);
        pack_t_kernel<<<dim3(12, 48), dim3(256), 0, stream>>>(w1 + lw * EE * FFD, FFD, W1t, EE);
        pack_t_kernel<<<dim3(48, 12), dim3(256), 0, stream>>>(w2 + lw * FFD * EE, EE, W2t, FFD);

        ln_kernel<<<dim3(TT), dim3(256), 0, stream>>>(x, ln1g + lw * EE, ln1b + lw * EE, h_bf);
        gemm_bf16<0><<<dim3(288), dim3(256), 0, stream>>>(
            h_bf, Wqkv, bq + lw * EE, bk + lw * EE, bv + lw * EE, nullptr, qkvb,
            QKVN, EE, 16, 1, EE);
        vtrans_kernel<<<dim3(768), dim3(256), 0, stream>>>(qkvb, vTb);
        attn_mfma<<<dim3(384), dim3(256), 0, stream>>>(qkvb, vTb, o_bf);
        gemm_bf16<1><<<dim3(384), dim3(256), 0, stream>>>(
            o_bf, Wproj, bproj + lw * EE, nullptr, nullptr, x, nullptr,
            EE, EE, 16, 4, 192);
        ln_kernel<<<dim3(TT), dim3(256), 0, stream>>>(x, ln2g + lw * EE, ln2b + lw * EE, h_bf);
        gemm_bf16<2><<<dim3(384), dim3(256), 0, stream>>>(
            h_bf, W1t, b1 + lw * FFD, nullptr, nullptr, nullptr, ffb,
            FFD, EE, 16, 1, EE);
        gemm_bf16<1><<<dim3(384), dim3(256), 0, stream>>>(
            ffb, W2t, b2 + lw * EE, nullptr, nullptr, x, nullptr,
            EE, FFD, 16, 4, 768);
    }

    ln_kernel<<<dim3(TT), dim3(256), 0, stream>>>(x, lnfg, lnfb, h_bf);
    pack_t_kernel<<<dim3(12, 48), dim3(256), 0, stream>>>(fw1, FFD, W1t, EE);
    pack_t_kernel<<<dim3(48, 12), dim3(256), 0, stream>>>(fw2, EE, W2t, FFD);
    gemm_bf16<2><<<dim3(384), dim3(256), 0, stream>>>(
        h_bf, W1t, fb1, nullptr, nullptr, nullptr, ffb, FFD, EE, 16, 1, EE);
    gemm_bf16<3><<<dim3(96), dim3(256), 0, stream>>>(
        ffb, W2t, fb2, nullptr, nullptr, x, nullptr, EE, FFD, 16, 1, FFD);
    head_kernel<<<dim3(TT), dim3(256), 0, stream>>>(x, hw, hb, out);
}